// Round 14
// baseline (446.029 us; speedup 1.0000x reference)
//
#include <hip/hip_runtime.h>
#include <hip/hip_bf16.h>
#include <math.h>

#define FIN 32
#define EFD 16
#define GDIM 8
#define ISPLIT 2
// D = 64, DL = 128 hard-coded throughout

typedef __attribute__((ext_vector_type(8))) short short8;   // 8 bf16 = 4 VGPRs (MFMA A/B frag)
typedef __attribute__((ext_vector_type(4))) float f32x4;    // MFMA C/D frag

static __device__ __forceinline__ float bf2f(unsigned short u) {
  return __uint_as_float(((unsigned)u) << 16);
}
static __device__ __forceinline__ unsigned short f2bf(float f) {
  unsigned u = __float_as_uint(f);
  unsigned r = (u + 0x7FFFu + ((u >> 16) & 1u)) >> 16;  // RNE
  return (unsigned short)r;
}

__global__ void zero_f32(float* __restrict__ p, int n) {
  int i = blockIdx.x * blockDim.x + threadIdx.x;
  if (i < n) p[i] = 0.0f;
}

__global__ void deg_kernel(const int* __restrict__ dst, float* __restrict__ deg, int E) {
  int e = blockIdx.x * blockDim.x + threadIdx.x;
  if (e < E) atomicAdd(&deg[dst[e]], 1.0f);
}

// One launch covering 4 independent setup jobs, partitioned by blockIdx range.
__global__ void setup_fused(const float* __restrict__ ea, const float* __restrict__ We1,
                            const float* __restrict__ be1, unsigned short* __restrict__ hidden,
                            const float* __restrict__ We2, unsigned short* __restrict__ We2f,
                            const float* __restrict__ Wroot, const float* __restrict__ W_hh,
                            const float* __restrict__ be2, const float* __restrict__ W_ih,
                            unsigned short* __restrict__ Wc_fh, unsigned short* __restrict__ Wc_fl,
                            unsigned short* __restrict__ Wih_fh, unsigned short* __restrict__ Wih_fl,
                            const float* __restrict__ x, const float* __restrict__ W0,
                            const float* __restrict__ b0, float* __restrict__ state,
                            int E, int N, int eB, int cB, int pB) {
  int b = blockIdx.x;
  if (b < eB) {
    int idx = b * 256 + threadIdx.x;
    int e = idx >> 7, l = idx & 127;
    if (e >= E) return;
    float acc = be1[l];
    const float* er = ea + (size_t)e * EFD;
    const float* wr = We1 + (size_t)l * EFD;
    #pragma unroll
    for (int j = 0; j < EFD; ++j) acc += er[j] * wr[j];
    hidden[idx] = f2bf(fmaxf(acc, 0.0f));
    return;
  }
  b -= eB;
  if (b < cB) {
    int fidx = b * 256 + threadIdx.x;
    if (fidx >= 4096 * 128) return;
    int j    = fidx & 7;
    int lane = (fidx >> 3) & 63;
    int kk   = (fidx >> 9) & 3;
    int wave = (fidx >> 11) & 3;
    int i    = fidx >> 13;
    int quad = lane >> 4, col = lane & 15;
    int row  = i * 64 + wave * 16 + col;    // 0..4095
    int cw   = kk * 32 + quad * 8 + j;      // 0..127
    We2f[fidx] = f2bf(We2[(size_t)row * 128 + cw]);
    return;
  }
  b -= cB;
  if (b < pB) {
    int idx = b * 256 + threadIdx.x;
    if (idx >= 20480 + 12288) return;
    if (idx < 20480) {
      int j = idx & 7, lane = (idx >> 3) & 63, kk = (idx >> 9) & 1, cgk = idx >> 10;  // 0..19
      int quad = lane >> 4, mcol = lane & 15;
      int wave = cgk / 5, cg = cgk % 5;
      int c = wave * 80 + cg * 16 + mcol;   // 0..319
      int cw = kk * 32 + quad * 8 + j;      // 0..63
      float w;
      if (c < 64)       w = Wroot[c * 64 + cw];
      else if (c < 256) w = W_hh[(c - 64) * 64 + cw];
      else              w = be2[cw * 64 + (c - 256)];
      unsigned short h = f2bf(w);
      Wc_fh[idx] = h;
      Wc_fl[idx] = f2bf(w - bf2f(h));
    } else {
      int t = idx - 20480;
      int j = t & 7, lane = (t >> 3) & 63, kk = (t >> 9) & 1, gw = t >> 10;  // 0..11
      int quad = lane >> 4, mcol = lane & 15;
      int g = gw >> 2, wave = gw & 3;
      int row = g * 64 + wave * 16 + mcol;
      int cw = kk * 32 + quad * 8 + j;
      float w = W_ih[row * 64 + cw];
      unsigned short h = f2bf(w);
      Wih_fh[t] = h;
      Wih_fl[t] = f2bf(w - bf2f(h));
    }
    return;
  }
  b -= pB;
  {
    int idx = b * 256 + threadIdx.x;
    int n = idx >> 6, d = idx & 63;
    if (n >= N) return;
    float acc = b0[d];
    const float* xr = x + (size_t)n * FIN;
    const float* wr = W0 + (size_t)d * FIN;
    #pragma unroll
    for (int f = 0; f < FIN; ++f) acc += xr[f] * wr[f];
    state[idx] = fmaxf(acc, 0.0f);
  }
}

#define MFMA(A, B, C) __builtin_amdgcn_mfma_f32_16x16x32_bf16((A), (B), (C), 0, 0, 0)

// R[N,320] = state @ Wc^T (hi/lo split). 32 nodes/block.
__global__ __launch_bounds__(256) void pre_kernel(const float* __restrict__ state,
    const unsigned short* __restrict__ Wc_fh, const unsigned short* __restrict__ Wc_fl,
    float* __restrict__ R, int N) {
  __shared__ __align__(16) unsigned short Sh[32 * 72], Sl[32 * 72];
  int tid = threadIdx.x;
  int n0 = blockIdx.x * 32;
  {
    int nl = tid >> 3, part = tid & 7;  // 8 threads/row, 8 cols each
    int gn = n0 + nl;
    const float* sp = state + (size_t)gn * 64 + part * 8;
    #pragma unroll
    for (int j = 0; j < 2; ++j) {
      float4 v = make_float4(0.f, 0.f, 0.f, 0.f);
      if (gn < N) v = *(const float4*)(sp + j * 4);
      int base = nl * 72 + part * 8 + j * 4;
      unsigned short h;
      h = f2bf(v.x); Sh[base + 0] = h; Sl[base + 0] = f2bf(v.x - bf2f(h));
      h = f2bf(v.y); Sh[base + 1] = h; Sl[base + 1] = f2bf(v.y - bf2f(h));
      h = f2bf(v.z); Sh[base + 2] = h; Sl[base + 2] = f2bf(v.z - bf2f(h));
      h = f2bf(v.w); Sh[base + 3] = h; Sl[base + 3] = f2bf(v.w - bf2f(h));
    }
  }
  __syncthreads();
  int lane = tid & 63, wave = tid >> 6;
  int quad = lane >> 4, mcol = lane & 15;
  short8 ah[2][2], al[2][2];
  #pragma unroll
  for (int mt = 0; mt < 2; ++mt)
    #pragma unroll
    for (int kk = 0; kk < 2; ++kk) {
      ah[mt][kk] = *(const short8*)&Sh[(mt * 16 + mcol) * 72 + kk * 32 + quad * 8];
      al[mt][kk] = *(const short8*)&Sl[(mt * 16 + mcol) * 72 + kk * 32 + quad * 8];
    }
  int c0w = wave * 80;
  #pragma unroll 1
  for (int cg = 0; cg < 5; ++cg) {
    int c = c0w + cg * 16 + mcol;
    const unsigned short* bhp = Wc_fh + (size_t)(wave * 5 + cg) * 1024 + lane * 8;
    const unsigned short* blp = Wc_fl + (size_t)(wave * 5 + cg) * 1024 + lane * 8;
    short8 bh0 = *(const short8*)bhp, bh1 = *(const short8*)(bhp + 512);
    short8 bl0 = *(const short8*)blp, bl1 = *(const short8*)(blp + 512);
    #pragma unroll
    for (int mt = 0; mt < 2; ++mt) {
      f32x4 p = (f32x4){0.f, 0.f, 0.f, 0.f};
      p = MFMA(al[mt][0], bh0, p);
      p = MFMA(ah[mt][0], bl0, p);
      p = MFMA(ah[mt][0], bh0, p);
      p = MFMA(al[mt][1], bh1, p);
      p = MFMA(ah[mt][1], bl1, p);
      p = MFMA(ah[mt][1], bh1, p);
      #pragma unroll
      for (int r = 0; r < 4; ++r) {
        int row = n0 + mt * 16 + quad * 4 + r;
        if (row < N) R[(size_t)row * 320 + c] = p[r];
      }
    }
  }
}

// Fused NNConv message + scatter — R8/R10 K-loop UNTOUCHED (77 µs, VGPR 88).
// Changes vs R13: (1) u-bias term moved out of the epilogue into appended
// u-scatter blocks (blockIdx >= edgeBlocks*ISPLIT) in the SAME launch — the
// epilogue no longer does 16 scattered R loads, srcs[] removed; (2) nothing
// else. Negative results pinned: depth-2 prefetch (R9), separate-St prologue
// (R11), launch_bounds(256,6) spill collapse (R12), full unroll (R6).
__global__ __launch_bounds__(256) void msg_fused(const int* __restrict__ ei,
    const float* __restrict__ state, const unsigned short* __restrict__ hidden,
    const unsigned short* __restrict__ We2f, const float* __restrict__ R,
    float* __restrict__ agg, int E, int edgeBlocks) {
  int tid = threadIdx.x;
  int lane = tid & 63, wave = tid >> 6;
  int mb = edgeBlocks * ISPLIT;
  if ((int)blockIdx.x >= mb) {
    // ---- u-scatter range: agg[dst] += R[src, 256+lane], one wave per edge ----
    int e = (blockIdx.x - mb) * 4 + wave;
    if (e < E) {
      int src = ei[e], dst = ei[E + e];
      float val = R[(size_t)src * 320 + 256 + lane];
      atomicAdd(&agg[(size_t)dst * 64 + lane], val);
    }
    return;
  }
  __shared__ __align__(16) char smem[64 * 136 * 2];
  __shared__ int dsts[64];
  unsigned short* Hs = (unsigned short*)smem;
  float* St = (float*)smem;  // [i_local][e], 32*64*4 = 8192 <= 17408
  int by = blockIdx.x / edgeBlocks;   // i-split (x-fast order, as R10's dim3)
  int bx = blockIdx.x % edgeBlocks;   // edge-block
  int e0 = bx * 64;
  int i0 = by * 32;  // this block's fold range [i0, i0+32)
  int snL;
  {
    int eL = e0 + lane;
    snL = (eL < E) ? ei[eL] : -1;
    if (tid < 64) dsts[tid] = (eL < E) ? ei[E + eL] : -1;
  }
  {
    int er = tid >> 2, part = tid & 3;
    int ge = e0 + er;
    const unsigned short* hp = hidden + (size_t)ge * 128 + part * 32;
    #pragma unroll
    for (int j = 0; j < 4; ++j) {
      uint4 v = make_uint4(0u, 0u, 0u, 0u);
      if (ge < E) v = *(const uint4*)(hp + j * 8);
      *(uint4*)&Hs[er * 136 + part * 32 + j * 8] = v;
    }
  }
  __syncthreads();
  int n0 = wave * 16;
  int quad = lane >> 4, col = lane & 15;
  short8 a[4][4];
  #pragma unroll
  for (int mt = 0; mt < 4; ++mt)
    #pragma unroll
    for (int kk = 0; kk < 4; ++kk)
      a[mt][kk] = *(const short8*)&Hs[(mt * 16 + col) * 136 + kk * 32 + quad * 8];
  // gather s for i_local range [wave*8, wave*8+8), lane = edge (own src index)
  float4 sreg[2];
  {
    const float* sp = state + (size_t)(snL < 0 ? 0 : snL) * 64 + i0 + wave * 8;
    #pragma unroll
    for (int j = 0; j < 2; ++j) {
      float4 v = make_float4(0.f, 0.f, 0.f, 0.f);
      if (snL >= 0) v = *(const float4*)(sp + j * 4);
      sreg[j] = v;
    }
  }
  __syncthreads();  // Hs reads retired -> safe to overwrite with St
  #pragma unroll
  for (int j = 0; j < 2; ++j) {
    int i = wave * 8 + j * 4;
    St[(i + 0) * 64 + lane] = sreg[j].x;
    St[(i + 1) * 64 + lane] = sreg[j].y;
    St[(i + 2) * 64 + lane] = sreg[j].z;
    St[(i + 3) * 64 + lane] = sreg[j].w;
  }
  __syncthreads();

  f32x4 macc0 = (f32x4){0.f,0.f,0.f,0.f}, macc1 = (f32x4){0.f,0.f,0.f,0.f};
  f32x4 macc2 = (f32x4){0.f,0.f,0.f,0.f}, macc3 = (f32x4){0.f,0.f,0.f,0.f};
  // fragment-major: addr = (i0+il)*8192 + wave*2048 + kk*512 + lane*8
  const unsigned short* bptr = We2f + (size_t)i0 * 8192 + wave * 2048 + lane * 8;
  short8 Xa = *(const short8*)(bptr + 0);
  short8 Xb = *(const short8*)(bptr + 512);
  short8 Xc = *(const short8*)(bptr + 1024);
  short8 Xd = *(const short8*)(bptr + 1536);
  short8 Ya, Yb, Yc, Yd;
  #pragma unroll 1
  for (int ii = 0; ii < 16; ++ii) {
    int i = ii * 2;
    {
      const unsigned short* bn = bptr + (size_t)(i + 1) * 8192;
      Ya = *(const short8*)(bn + 0);
      Yb = *(const short8*)(bn + 512);
      Yc = *(const short8*)(bn + 1024);
      Yd = *(const short8*)(bn + 1536);
    }
    {
      f32x4 sv0 = *(const f32x4*)&St[i * 64 +  0 + quad * 4];
      f32x4 sv1 = *(const f32x4*)&St[i * 64 + 16 + quad * 4];
      f32x4 sv2 = *(const f32x4*)&St[i * 64 + 32 + quad * 4];
      f32x4 sv3 = *(const f32x4*)&St[i * 64 + 48 + quad * 4];
      f32x4 p0 = (f32x4){0.f,0.f,0.f,0.f}, p1 = (f32x4){0.f,0.f,0.f,0.f};
      f32x4 p2 = (f32x4){0.f,0.f,0.f,0.f}, p3 = (f32x4){0.f,0.f,0.f,0.f};
      p0 = MFMA(a[0][0], Xa, p0); p1 = MFMA(a[1][0], Xa, p1);
      p2 = MFMA(a[2][0], Xa, p2); p3 = MFMA(a[3][0], Xa, p3);
      p0 = MFMA(a[0][1], Xb, p0); p1 = MFMA(a[1][1], Xb, p1);
      p2 = MFMA(a[2][1], Xb, p2); p3 = MFMA(a[3][1], Xb, p3);
      p0 = MFMA(a[0][2], Xc, p0); p1 = MFMA(a[1][2], Xc, p1);
      p2 = MFMA(a[2][2], Xc, p2); p3 = MFMA(a[3][2], Xc, p3);
      p0 = MFMA(a[0][3], Xd, p0); p1 = MFMA(a[1][3], Xd, p1);
      p2 = MFMA(a[2][3], Xd, p2); p3 = MFMA(a[3][3], Xd, p3);
      macc0 += sv0 * p0; macc1 += sv1 * p1; macc2 += sv2 * p2; macc3 += sv3 * p3;
    }
    if (ii < 15) {
      const unsigned short* bn = bptr + (size_t)(i + 2) * 8192;
      Xa = *(const short8*)(bn + 0);
      Xb = *(const short8*)(bn + 512);
      Xc = *(const short8*)(bn + 1024);
      Xd = *(const short8*)(bn + 1536);
    }
    {
      int io = i + 1;
      f32x4 sv0 = *(const f32x4*)&St[io * 64 +  0 + quad * 4];
      f32x4 sv1 = *(const f32x4*)&St[io * 64 + 16 + quad * 4];
      f32x4 sv2 = *(const f32x4*)&St[io * 64 + 32 + quad * 4];
      f32x4 sv3 = *(const f32x4*)&St[io * 64 + 48 + quad * 4];
      f32x4 p0 = (f32x4){0.f,0.f,0.f,0.f}, p1 = (f32x4){0.f,0.f,0.f,0.f};
      f32x4 p2 = (f32x4){0.f,0.f,0.f,0.f}, p3 = (f32x4){0.f,0.f,0.f,0.f};
      p0 = MFMA(a[0][0], Ya, p0); p1 = MFMA(a[1][0], Ya, p1);
      p2 = MFMA(a[2][0], Ya, p2); p3 = MFMA(a[3][0], Ya, p3);
      p0 = MFMA(a[0][1], Yb, p0); p1 = MFMA(a[1][1], Yb, p1);
      p2 = MFMA(a[2][1], Yb, p2); p3 = MFMA(a[3][1], Yb, p3);
      p0 = MFMA(a[0][2], Yc, p0); p1 = MFMA(a[1][2], Yc, p1);
      p2 = MFMA(a[2][2], Yc, p2); p3 = MFMA(a[3][2], Yc, p3);
      p0 = MFMA(a[0][3], Yd, p0); p1 = MFMA(a[1][3], Yd, p1);
      p2 = MFMA(a[2][3], Yd, p2); p3 = MFMA(a[3][3], Yd, p3);
      macc0 += sv0 * p0; macc1 += sv1 * p1; macc2 += sv2 * p2; macc3 += sv3 * p3;
    }
  }
  f32x4 maccA[4] = {macc0, macc1, macc2, macc3};
  #pragma unroll
  for (int mt = 0; mt < 4; ++mt) {
    #pragma unroll
    for (int r = 0; r < 4; ++r) {
      int el = mt * 16 + quad * 4 + r;
      int d = dsts[el];
      if (d >= 0)
        atomicAdd(&agg[(size_t)d * 64 + n0 + col], maccA[mt][r]);
    }
  }
}

// Fused: m = relu(agg/deg + R.root + bconv); gi = m@W_ih^T; gates; re-zero agg;
// then either next iteration's R = h_new @ Wc^T (do_pre), or the output head
// (final iteration): out = relu(cat(h,ga[batch])@W1^T+b1)@W2+b2 via LDS h.
// 16 nodes/block (626 blocks) — latency-bound, more blocks = more waves (R9/R13).
__global__ __launch_bounds__(256) void gate_pre(float* __restrict__ agg,
    const float* __restrict__ deg, float* __restrict__ state,
    float* __restrict__ R, const float* __restrict__ bconv,
    const unsigned short* __restrict__ Wih_fh, const unsigned short* __restrict__ Wih_fl,
    const float* __restrict__ b_ih, const float* __restrict__ b_hh,
    const unsigned short* __restrict__ Wc_fh, const unsigned short* __restrict__ Wc_fl,
    const int* __restrict__ batch, const float* __restrict__ gattr,
    const float* __restrict__ W1, const float* __restrict__ b1,
    const float* __restrict__ W2, const float* __restrict__ b2,
    float* __restrict__ out, int N, int do_pre) {
  __shared__ __align__(16) unsigned short Mh[16 * 72], Ml[16 * 72];
  int tid = threadIdx.x;
  int n0 = blockIdx.x * 16;
  {
    int nl = tid >> 4, part = tid & 15;  // 16 threads/row, 4 cols each
    int gn = n0 + nl;
    float inv = 1.0f;
    if (gn < N) inv = 1.0f / fmaxf(deg[gn], 1.0f);
    int o = part * 4;
    float4 av = make_float4(0.f, 0.f, 0.f, 0.f);
    float4 rv = make_float4(0.f, 0.f, 0.f, 0.f);
    if (gn < N) {
      av = *(const float4*)(agg + (size_t)gn * 64 + o);
      rv = *(const float4*)(R + (size_t)gn * 320 + o);
    }
    float4 bv = *(const float4*)(bconv + o);
    float m0 = fmaxf(av.x * inv + rv.x + bv.x, 0.0f);
    float m1 = fmaxf(av.y * inv + rv.y + bv.y, 0.0f);
    float m2 = fmaxf(av.z * inv + rv.z + bv.z, 0.0f);
    float m3 = fmaxf(av.w * inv + rv.w + bv.w, 0.0f);
    int base = nl * 72 + o;
    unsigned short h;
    h = f2bf(m0); Mh[base + 0] = h; Ml[base + 0] = f2bf(m0 - bf2f(h));
    h = f2bf(m1); Mh[base + 1] = h; Ml[base + 1] = f2bf(m1 - bf2f(h));
    h = f2bf(m2); Mh[base + 2] = h; Ml[base + 2] = f2bf(m2 - bf2f(h));
    h = f2bf(m3); Mh[base + 3] = h; Ml[base + 3] = f2bf(m3 - bf2f(h));
    if (gn < N)
      *(float4*)(agg + (size_t)gn * 64 + o) = make_float4(0.f, 0.f, 0.f, 0.f);
  }
  __syncthreads();
  int lane = tid & 63, wave = tid >> 6;
  int quad = lane >> 4, mcol = lane & 15;
  short8 ah[2], al[2];
  #pragma unroll
  for (int kk = 0; kk < 2; ++kk) {
    ah[kk] = *(const short8*)&Mh[mcol * 72 + kk * 32 + quad * 8];
    al[kk] = *(const short8*)&Ml[mcol * 72 + kk * 32 + quad * 8];
  }
  int c = wave * 16 + mcol;
  f32x4 accg[3];
  #pragma unroll 1
  for (int g = 0; g < 3; ++g) {
    const unsigned short* bhp = Wih_fh + (size_t)g * 4096 + wave * 1024 + lane * 8;
    const unsigned short* blp = Wih_fl + (size_t)g * 4096 + wave * 1024 + lane * 8;
    short8 bh0 = *(const short8*)bhp, bh1 = *(const short8*)(bhp + 512);
    short8 bl0 = *(const short8*)blp, bl1 = *(const short8*)(blp + 512);
    f32x4 p = (f32x4){0.f, 0.f, 0.f, 0.f};
    p = MFMA(al[0], bh0, p);
    p = MFMA(ah[0], bl0, p);
    p = MFMA(ah[0], bh0, p);
    p = MFMA(al[1], bh1, p);
    p = MFMA(ah[1], bl1, p);
    p = MFMA(ah[1], bh1, p);
    accg[g] = p;
  }
  float bir = b_ih[c], biz = b_ih[64 + c], bin = b_ih[128 + c];
  float bhr = b_hh[c], bhz = b_hh[64 + c], bhn = b_hh[128 + c];
  float hnew[4];
  #pragma unroll
  for (int r = 0; r < 4; ++r) {
    int node = n0 + quad * 4 + r;
    hnew[r] = 0.0f;
    if (node >= N) continue;
    const float* Rn = R + (size_t)node * 320;
    float gir = accg[0][r] + bir + Rn[64 + c] + bhr;
    float giz = accg[1][r] + biz + Rn[128 + c] + bhz;
    float ghn = Rn[192 + c] + bhn;
    float rg = 1.0f / (1.0f + expf(-gir));
    float zg = 1.0f / (1.0f + expf(-giz));
    float ng = tanhf(accg[2][r] + bin + rg * ghn);
    size_t si = (size_t)node * 64 + c;
    float h = state[si];
    float hv = (1.0f - zg) * ng + zg * h;
    state[si] = hv;
    hnew[r] = hv;
  }
  if (do_pre) {
    __syncthreads();  // all Mh/Ml A-frag reads done -> reuse for h_new
    #pragma unroll
    for (int r = 0; r < 4; ++r) {
      int base = (quad * 4 + r) * 72 + c;
      float v = hnew[r];
      unsigned short h = f2bf(v);
      Mh[base] = h; Ml[base] = f2bf(v - bf2f(h));
    }
    __syncthreads();
    // pre phase: R = h_new @ Wc^T ; wave covers cols [80w, 80w+80)
    short8 ph[2], pl[2];
    #pragma unroll
    for (int kk = 0; kk < 2; ++kk) {
      ph[kk] = *(const short8*)&Mh[mcol * 72 + kk * 32 + quad * 8];
      pl[kk] = *(const short8*)&Ml[mcol * 72 + kk * 32 + quad * 8];
    }
    #pragma unroll 1
    for (int cg = 0; cg < 5; ++cg) {
      int cc = wave * 80 + cg * 16 + mcol;
      const unsigned short* bhp = Wc_fh + (size_t)(wave * 5 + cg) * 1024 + lane * 8;
      const unsigned short* blp = Wc_fl + (size_t)(wave * 5 + cg) * 1024 + lane * 8;
      short8 bh0 = *(const short8*)bhp, bh1 = *(const short8*)(bhp + 512);
      short8 bl0 = *(const short8*)blp, bl1 = *(const short8*)(blp + 512);
      f32x4 p = (f32x4){0.f, 0.f, 0.f, 0.f};
      p = MFMA(pl[0], bh0, p);
      p = MFMA(ph[0], bl0, p);
      p = MFMA(ph[0], bh0, p);
      p = MFMA(pl[1], bh1, p);
      p = MFMA(ph[1], bl1, p);
      p = MFMA(ph[1], bh1, p);
      #pragma unroll
      for (int r = 0; r < 4; ++r) {
        int row = n0 + quad * 4 + r;
        if (row < N) R[(size_t)row * 320 + cc] = p[r];
      }
    }
  } else {
    // ---- final head fused into the last gate (h_new via LDS as fp32) ----
    __syncthreads();  // Mh/Ml dead -> overlay Hf
    float* Hf = (float*)Mh;  // 16*64 floats = 4096 B <= Mh's 4608 B
    #pragma unroll
    for (int r = 0; r < 4; ++r)
      Hf[(quad * 4 + r) * 64 + c] = hnew[r];
    __syncthreads();
    const float* w = W1 + (size_t)lane * 72;
    #pragma unroll 1
    for (int nl = 0; nl < 4; ++nl) {
      int node_local = wave * 4 + nl;
      int node = n0 + node_local;
      if (node >= N) continue;
      float s = Hf[node_local * 64 + lane];
      int b = batch[node];
      float acc = b1[lane];
      for (int i = 0; i < 64; ++i) acc += __shfl(s, i) * w[i];
      const float* gar = gattr + (size_t)b * GDIM;
      #pragma unroll
      for (int j = 0; j < GDIM; ++j) acc += gar[j] * w[64 + j];
      float hid = fmaxf(acc, 0.0f);
      float v = hid * W2[lane];
      #pragma unroll
      for (int off = 32; off > 0; off >>= 1) v += __shfl_xor(v, off);
      if (lane == 0) out[node] = v + b2[0];
    }
  }
}

extern "C" void kernel_launch(void* const* d_in, const int* in_sizes, int n_in,
                              void* d_out, int out_size, void* d_ws, size_t ws_size,
                              hipStream_t stream) {
  const float* x     = (const float*)d_in[0];
  const int*   ei    = (const int*)d_in[1];
  const float* ea    = (const float*)d_in[2];
  const int*   batch = (const int*)d_in[3];
  const float* ga    = (const float*)d_in[4];
  const float* W0    = (const float*)d_in[5];
  const float* b0    = (const float*)d_in[6];
  const float* We1   = (const float*)d_in[7];
  const float* be1   = (const float*)d_in[8];
  const float* We2   = (const float*)d_in[9];
  const float* be2   = (const float*)d_in[10];
  const float* Wroot = (const float*)d_in[11];
  const float* bconv = (const float*)d_in[12];
  const float* W_ih  = (const float*)d_in[13];
  const float* W_hh  = (const float*)d_in[14];
  const float* b_ih  = (const float*)d_in[15];
  const float* b_hh  = (const float*)d_in[16];
  const float* W1    = (const float*)d_in[17];
  const float* b1    = (const float*)d_in[18];
  const float* W2    = (const float*)d_in[19];
  const float* b2    = (const float*)d_in[20];
  int N = in_sizes[0] / FIN;
  int E = in_sizes[1] / 2;
  float* out = (float*)d_out;

  char* p = (char*)d_ws;
  float* state = (float*)p; p += (size_t)N * 64 * 4;
  float* agg   = (float*)p; p += (size_t)N * 64 * 4;
  float* deg   = (float*)p; p += ((size_t)N * 4 + 15) & ~(size_t)15;
  float* R     = (float*)p; p += (size_t)N * 320 * 4;
  unsigned short* hidden = (unsigned short*)p; p += (size_t)E * 128 * 2;
  unsigned short* We2f   = (unsigned short*)p; p += (size_t)4096 * 128 * 2;
  unsigned short* Wc_fh  = (unsigned short*)p; p += 320 * 64 * 2;
  unsigned short* Wc_fl  = (unsigned short*)p; p += 320 * 64 * 2;
  unsigned short* Wih_fh = (unsigned short*)p; p += 192 * 64 * 2;
  unsigned short* Wih_fl = (unsigned short*)p; p += 192 * 64 * 2;

  int tileBlocks32 = (N + 31) / 32;
  int tileBlocks16 = (N + 15) / 16;
  int edgeBlocks = (E + 63) / 64;
  int uBlocks = (E + 3) / 4;

  int eB = (E * 128 + 255) / 256;
  int cB = (4096 * 128 + 255) / 256;
  int pB = (32768 + 255) / 256;
  int lB = (N * 64 + 255) / 256;

  zero_f32<<<(N * 65 + 255) / 256, 256, 0, stream>>>(agg, N * 65);  // agg + deg contiguous
  deg_kernel<<<(E + 255) / 256, 256, 0, stream>>>(ei + E, deg, E);
  setup_fused<<<eB + cB + pB + lB, 256, 0, stream>>>(
      ea, We1, be1, hidden, We2, We2f, Wroot, W_hh, be2, W_ih,
      Wc_fh, Wc_fl, Wih_fh, Wih_fl, x, W0, b0, state, E, N, eB, cB, pB);
  pre_kernel<<<tileBlocks32, 256, 0, stream>>>(state, Wc_fh, Wc_fl, R, N);
  for (int t = 0; t < 3; ++t) {
    msg_fused<<<edgeBlocks * ISPLIT + uBlocks, 256, 0, stream>>>(
        ei, state, hidden, We2f, R, agg, E, edgeBlocks);
    gate_pre<<<tileBlocks16, 256, 0, stream>>>(agg, deg, state, R, bconv,
                                               Wih_fh, Wih_fl, b_ih, b_hh,
                                               Wc_fh, Wc_fl, batch, ga,
                                               W1, b1, W2, b2, out,
                                               N, (t < 2) ? 1 : 0);
  }
}

// Round 15
// 412.807 us; speedup vs baseline: 1.0805x; 1.0805x over previous
//
#include <hip/hip_runtime.h>
#include <hip/hip_bf16.h>
#include <math.h>

#define FIN 32
#define EFD 16
#define GDIM 8
#define ISPLIT 2
// D = 64, DL = 128 hard-coded throughout

typedef __attribute__((ext_vector_type(8))) short short8;   // 8 bf16 = 4 VGPRs (MFMA A/B frag)
typedef __attribute__((ext_vector_type(4))) float f32x4;    // MFMA C/D frag

static __device__ __forceinline__ float bf2f(unsigned short u) {
  return __uint_as_float(((unsigned)u) << 16);
}
static __device__ __forceinline__ unsigned short f2bf(float f) {
  unsigned u = __float_as_uint(f);
  unsigned r = (u + 0x7FFFu + ((u >> 16) & 1u)) >> 16;  // RNE
  return (unsigned short)r;
}

__global__ void zero_f32(float* __restrict__ p, int n) {
  int i = blockIdx.x * blockDim.x + threadIdx.x;
  if (i < n) p[i] = 0.0f;
}

__global__ void deg_kernel(const int* __restrict__ dst, float* __restrict__ deg, int E) {
  int e = blockIdx.x * blockDim.x + threadIdx.x;
  if (e < E) atomicAdd(&deg[dst[e]], 1.0f);
}

// One launch covering 4 independent setup jobs, partitioned by blockIdx range.
__global__ void setup_fused(const float* __restrict__ ea, const float* __restrict__ We1,
                            const float* __restrict__ be1, unsigned short* __restrict__ hidden,
                            const float* __restrict__ We2, unsigned short* __restrict__ We2f,
                            const float* __restrict__ Wroot, const float* __restrict__ W_hh,
                            const float* __restrict__ be2, const float* __restrict__ W_ih,
                            unsigned short* __restrict__ Wc_fh, unsigned short* __restrict__ Wc_fl,
                            unsigned short* __restrict__ Wih_fh, unsigned short* __restrict__ Wih_fl,
                            const float* __restrict__ x, const float* __restrict__ W0,
                            const float* __restrict__ b0, float* __restrict__ state,
                            int E, int N, int eB, int cB, int pB) {
  int b = blockIdx.x;
  if (b < eB) {
    int idx = b * 256 + threadIdx.x;
    int e = idx >> 7, l = idx & 127;
    if (e >= E) return;
    float acc = be1[l];
    const float* er = ea + (size_t)e * EFD;
    const float* wr = We1 + (size_t)l * EFD;
    #pragma unroll
    for (int j = 0; j < EFD; ++j) acc += er[j] * wr[j];
    hidden[idx] = f2bf(fmaxf(acc, 0.0f));
    return;
  }
  b -= eB;
  if (b < cB) {
    int fidx = b * 256 + threadIdx.x;
    if (fidx >= 4096 * 128) return;
    int j    = fidx & 7;
    int lane = (fidx >> 3) & 63;
    int kk   = (fidx >> 9) & 3;
    int wave = (fidx >> 11) & 3;
    int i    = fidx >> 13;
    int quad = lane >> 4, col = lane & 15;
    int row  = i * 64 + wave * 16 + col;    // 0..4095
    int cw   = kk * 32 + quad * 8 + j;      // 0..127
    We2f[fidx] = f2bf(We2[(size_t)row * 128 + cw]);
    return;
  }
  b -= cB;
  if (b < pB) {
    int idx = b * 256 + threadIdx.x;
    if (idx >= 20480 + 12288) return;
    if (idx < 20480) {
      int j = idx & 7, lane = (idx >> 3) & 63, kk = (idx >> 9) & 1, cgk = idx >> 10;  // 0..19
      int quad = lane >> 4, mcol = lane & 15;
      int wave = cgk / 5, cg = cgk % 5;
      int c = wave * 80 + cg * 16 + mcol;   // 0..319
      int cw = kk * 32 + quad * 8 + j;      // 0..63
      float w;
      if (c < 64)       w = Wroot[c * 64 + cw];
      else if (c < 256) w = W_hh[(c - 64) * 64 + cw];
      else              w = be2[cw * 64 + (c - 256)];
      unsigned short h = f2bf(w);
      Wc_fh[idx] = h;
      Wc_fl[idx] = f2bf(w - bf2f(h));
    } else {
      int t = idx - 20480;
      int j = t & 7, lane = (t >> 3) & 63, kk = (t >> 9) & 1, gw = t >> 10;  // 0..11
      int quad = lane >> 4, mcol = lane & 15;
      int g = gw >> 2, wave = gw & 3;
      int row = g * 64 + wave * 16 + mcol;
      int cw = kk * 32 + quad * 8 + j;
      float w = W_ih[row * 64 + cw];
      unsigned short h = f2bf(w);
      Wih_fh[t] = h;
      Wih_fl[t] = f2bf(w - bf2f(h));
    }
    return;
  }
  b -= pB;
  {
    int idx = b * 256 + threadIdx.x;
    int n = idx >> 6, d = idx & 63;
    if (n >= N) return;
    float acc = b0[d];
    const float* xr = x + (size_t)n * FIN;
    const float* wr = W0 + (size_t)d * FIN;
    #pragma unroll
    for (int f = 0; f < FIN; ++f) acc += xr[f] * wr[f];
    state[idx] = fmaxf(acc, 0.0f);
  }
}

#define MFMA(A, B, C) __builtin_amdgcn_mfma_f32_16x16x32_bf16((A), (B), (C), 0, 0, 0)

// R[N,320] = state @ Wc^T (hi/lo split). 32 nodes/block.
__global__ __launch_bounds__(256) void pre_kernel(const float* __restrict__ state,
    const unsigned short* __restrict__ Wc_fh, const unsigned short* __restrict__ Wc_fl,
    float* __restrict__ R, int N) {
  __shared__ __align__(16) unsigned short Sh[32 * 72], Sl[32 * 72];
  int tid = threadIdx.x;
  int n0 = blockIdx.x * 32;
  {
    int nl = tid >> 3, part = tid & 7;  // 8 threads/row, 8 cols each
    int gn = n0 + nl;
    const float* sp = state + (size_t)gn * 64 + part * 8;
    #pragma unroll
    for (int j = 0; j < 2; ++j) {
      float4 v = make_float4(0.f, 0.f, 0.f, 0.f);
      if (gn < N) v = *(const float4*)(sp + j * 4);
      int base = nl * 72 + part * 8 + j * 4;
      unsigned short h;
      h = f2bf(v.x); Sh[base + 0] = h; Sl[base + 0] = f2bf(v.x - bf2f(h));
      h = f2bf(v.y); Sh[base + 1] = h; Sl[base + 1] = f2bf(v.y - bf2f(h));
      h = f2bf(v.z); Sh[base + 2] = h; Sl[base + 2] = f2bf(v.z - bf2f(h));
      h = f2bf(v.w); Sh[base + 3] = h; Sl[base + 3] = f2bf(v.w - bf2f(h));
    }
  }
  __syncthreads();
  int lane = tid & 63, wave = tid >> 6;
  int quad = lane >> 4, mcol = lane & 15;
  short8 ah[2][2], al[2][2];
  #pragma unroll
  for (int mt = 0; mt < 2; ++mt)
    #pragma unroll
    for (int kk = 0; kk < 2; ++kk) {
      ah[mt][kk] = *(const short8*)&Sh[(mt * 16 + mcol) * 72 + kk * 32 + quad * 8];
      al[mt][kk] = *(const short8*)&Sl[(mt * 16 + mcol) * 72 + kk * 32 + quad * 8];
    }
  int c0w = wave * 80;
  #pragma unroll 1
  for (int cg = 0; cg < 5; ++cg) {
    int c = c0w + cg * 16 + mcol;
    const unsigned short* bhp = Wc_fh + (size_t)(wave * 5 + cg) * 1024 + lane * 8;
    const unsigned short* blp = Wc_fl + (size_t)(wave * 5 + cg) * 1024 + lane * 8;
    short8 bh0 = *(const short8*)bhp, bh1 = *(const short8*)(bhp + 512);
    short8 bl0 = *(const short8*)blp, bl1 = *(const short8*)(blp + 512);
    #pragma unroll
    for (int mt = 0; mt < 2; ++mt) {
      f32x4 p = (f32x4){0.f, 0.f, 0.f, 0.f};
      p = MFMA(al[mt][0], bh0, p);
      p = MFMA(ah[mt][0], bl0, p);
      p = MFMA(ah[mt][0], bh0, p);
      p = MFMA(al[mt][1], bh1, p);
      p = MFMA(ah[mt][1], bl1, p);
      p = MFMA(ah[mt][1], bh1, p);
      #pragma unroll
      for (int r = 0; r < 4; ++r) {
        int row = n0 + mt * 16 + quad * 4 + r;
        if (row < N) R[(size_t)row * 320 + c] = p[r];
      }
    }
  }
}

// Fused NNConv message + scatter — R8/R10/R13 configuration, UNTOUCHED (best
// measured: 78.7 µs, MfmaUtil 27.5%, VGPR 88, 5 waves/SIMD).
// Negative results pinned here: depth-2 prefetch → VGPR 132, regressed (R9);
// separate-St single-barrier prologue → VGPR 108 + LDS 26K, regressed (R11);
// __launch_bounds__(256,6) → allocator collapse to VGPR 40 + full spill (R12);
// u-bias extraction to appended blocks → dilution, regressed (R14);
// full unroll → 256 VGPR spill (R6). This is the structure's floor.
__global__ __launch_bounds__(256) void msg_fused(const int* __restrict__ ei,
    const float* __restrict__ state, const unsigned short* __restrict__ hidden,
    const unsigned short* __restrict__ We2f, const float* __restrict__ R,
    float* __restrict__ agg, int E) {
  __shared__ __align__(16) char smem[64 * 136 * 2];
  __shared__ int srcs[64], dsts[64];
  unsigned short* Hs = (unsigned short*)smem;
  float* St = (float*)smem;  // [i_local][e], 32*64*4 = 8192 <= 17408
  int tid = threadIdx.x;
  int e0 = blockIdx.x * 64;
  int i0 = blockIdx.y * 32;  // this block's fold range [i0, i0+32)
  if (tid < 64) {
    int e = e0 + tid;
    srcs[tid] = (e < E) ? ei[e] : -1;
    dsts[tid] = (e < E) ? ei[E + e] : -1;
  }
  {
    int er = tid >> 2, part = tid & 3;
    int ge = e0 + er;
    const unsigned short* hp = hidden + (size_t)ge * 128 + part * 32;
    #pragma unroll
    for (int j = 0; j < 4; ++j) {
      uint4 v = make_uint4(0u, 0u, 0u, 0u);
      if (ge < E) v = *(const uint4*)(hp + j * 8);
      *(uint4*)&Hs[er * 136 + part * 32 + j * 8] = v;
    }
  }
  __syncthreads();
  int lane = tid & 63, wave = tid >> 6;
  int n0 = wave * 16;
  int quad = lane >> 4, col = lane & 15;
  short8 a[4][4];
  #pragma unroll
  for (int mt = 0; mt < 4; ++mt)
    #pragma unroll
    for (int kk = 0; kk < 4; ++kk)
      a[mt][kk] = *(const short8*)&Hs[(mt * 16 + col) * 136 + kk * 32 + quad * 8];
  // gather s for i_local range [wave*8, wave*8+8), lane = edge
  float4 sreg[2];
  {
    int sn = srcs[lane];
    const float* sp = state + (size_t)(sn < 0 ? 0 : sn) * 64 + i0 + wave * 8;
    #pragma unroll
    for (int j = 0; j < 2; ++j) {
      float4 v = make_float4(0.f, 0.f, 0.f, 0.f);
      if (sn >= 0) v = *(const float4*)(sp + j * 4);
      sreg[j] = v;
    }
  }
  __syncthreads();  // Hs reads retired -> safe to overwrite with St
  #pragma unroll
  for (int j = 0; j < 2; ++j) {
    int i = wave * 8 + j * 4;
    St[(i + 0) * 64 + lane] = sreg[j].x;
    St[(i + 1) * 64 + lane] = sreg[j].y;
    St[(i + 2) * 64 + lane] = sreg[j].z;
    St[(i + 3) * 64 + lane] = sreg[j].w;
  }
  __syncthreads();

  f32x4 macc0 = (f32x4){0.f,0.f,0.f,0.f}, macc1 = (f32x4){0.f,0.f,0.f,0.f};
  f32x4 macc2 = (f32x4){0.f,0.f,0.f,0.f}, macc3 = (f32x4){0.f,0.f,0.f,0.f};
  // fragment-major: addr = (i0+il)*8192 + wave*2048 + kk*512 + lane*8
  const unsigned short* bptr = We2f + (size_t)i0 * 8192 + wave * 2048 + lane * 8;
  short8 Xa = *(const short8*)(bptr + 0);
  short8 Xb = *(const short8*)(bptr + 512);
  short8 Xc = *(const short8*)(bptr + 1024);
  short8 Xd = *(const short8*)(bptr + 1536);
  short8 Ya, Yb, Yc, Yd;
  #pragma unroll 1
  for (int ii = 0; ii < 16; ++ii) {
    int i = ii * 2;
    {
      const unsigned short* bn = bptr + (size_t)(i + 1) * 8192;
      Ya = *(const short8*)(bn + 0);
      Yb = *(const short8*)(bn + 512);
      Yc = *(const short8*)(bn + 1024);
      Yd = *(const short8*)(bn + 1536);
    }
    {
      f32x4 sv0 = *(const f32x4*)&St[i * 64 +  0 + quad * 4];
      f32x4 sv1 = *(const f32x4*)&St[i * 64 + 16 + quad * 4];
      f32x4 sv2 = *(const f32x4*)&St[i * 64 + 32 + quad * 4];
      f32x4 sv3 = *(const f32x4*)&St[i * 64 + 48 + quad * 4];
      f32x4 p0 = (f32x4){0.f,0.f,0.f,0.f}, p1 = (f32x4){0.f,0.f,0.f,0.f};
      f32x4 p2 = (f32x4){0.f,0.f,0.f,0.f}, p3 = (f32x4){0.f,0.f,0.f,0.f};
      p0 = MFMA(a[0][0], Xa, p0); p1 = MFMA(a[1][0], Xa, p1);
      p2 = MFMA(a[2][0], Xa, p2); p3 = MFMA(a[3][0], Xa, p3);
      p0 = MFMA(a[0][1], Xb, p0); p1 = MFMA(a[1][1], Xb, p1);
      p2 = MFMA(a[2][1], Xb, p2); p3 = MFMA(a[3][1], Xb, p3);
      p0 = MFMA(a[0][2], Xc, p0); p1 = MFMA(a[1][2], Xc, p1);
      p2 = MFMA(a[2][2], Xc, p2); p3 = MFMA(a[3][2], Xc, p3);
      p0 = MFMA(a[0][3], Xd, p0); p1 = MFMA(a[1][3], Xd, p1);
      p2 = MFMA(a[2][3], Xd, p2); p3 = MFMA(a[3][3], Xd, p3);
      macc0 += sv0 * p0; macc1 += sv1 * p1; macc2 += sv2 * p2; macc3 += sv3 * p3;
    }
    if (ii < 15) {
      const unsigned short* bn = bptr + (size_t)(i + 2) * 8192;
      Xa = *(const short8*)(bn + 0);
      Xb = *(const short8*)(bn + 512);
      Xc = *(const short8*)(bn + 1024);
      Xd = *(const short8*)(bn + 1536);
    }
    {
      int io = i + 1;
      f32x4 sv0 = *(const f32x4*)&St[io * 64 +  0 + quad * 4];
      f32x4 sv1 = *(const f32x4*)&St[io * 64 + 16 + quad * 4];
      f32x4 sv2 = *(const f32x4*)&St[io * 64 + 32 + quad * 4];
      f32x4 sv3 = *(const f32x4*)&St[io * 64 + 48 + quad * 4];
      f32x4 p0 = (f32x4){0.f,0.f,0.f,0.f}, p1 = (f32x4){0.f,0.f,0.f,0.f};
      f32x4 p2 = (f32x4){0.f,0.f,0.f,0.f}, p3 = (f32x4){0.f,0.f,0.f,0.f};
      p0 = MFMA(a[0][0], Ya, p0); p1 = MFMA(a[1][0], Ya, p1);
      p2 = MFMA(a[2][0], Ya, p2); p3 = MFMA(a[3][0], Ya, p3);
      p0 = MFMA(a[0][1], Yb, p0); p1 = MFMA(a[1][1], Yb, p1);
      p2 = MFMA(a[2][1], Yb, p2); p3 = MFMA(a[3][1], Yb, p3);
      p0 = MFMA(a[0][2], Yc, p0); p1 = MFMA(a[1][2], Yc, p1);
      p2 = MFMA(a[2][2], Yc, p2); p3 = MFMA(a[3][2], Yc, p3);
      p0 = MFMA(a[0][3], Yd, p0); p1 = MFMA(a[1][3], Yd, p1);
      p2 = MFMA(a[2][3], Yd, p2); p3 = MFMA(a[3][3], Yd, p3);
      macc0 += sv0 * p0; macc1 += sv1 * p1; macc2 += sv2 * p2; macc3 += sv3 * p3;
    }
  }
  int addu = (blockIdx.y == 0);
  f32x4 maccA[4] = {macc0, macc1, macc2, macc3};
  #pragma unroll
  for (int mt = 0; mt < 4; ++mt) {
    #pragma unroll
    for (int r = 0; r < 4; ++r) {
      int el = mt * 16 + quad * 4 + r;
      int d = dsts[el];
      if (d >= 0) {
        float val = maccA[mt][r];
        if (addu) val += R[(size_t)srcs[el] * 320 + 256 + n0 + col];
        atomicAdd(&agg[(size_t)d * 64 + n0 + col], val);
      }
    }
  }
}

// Fused: m = relu(agg/deg + R.root + bconv); gi = m@W_ih^T; gates; re-zero agg;
// then (if do_pre) next iteration's R = h_new @ Wc^T. 16 nodes/block (626
// blocks) — latency-bound, more blocks = more resident waves (R9's 64->32 win).
__global__ __launch_bounds__(256) void gate_pre(float* __restrict__ agg,
    const float* __restrict__ deg, float* __restrict__ state,
    float* __restrict__ R, const float* __restrict__ bconv,
    const unsigned short* __restrict__ Wih_fh, const unsigned short* __restrict__ Wih_fl,
    const float* __restrict__ b_ih, const float* __restrict__ b_hh,
    const unsigned short* __restrict__ Wc_fh, const unsigned short* __restrict__ Wc_fl,
    int N, int do_pre) {
  __shared__ __align__(16) unsigned short Mh[16 * 72], Ml[16 * 72];
  int tid = threadIdx.x;
  int n0 = blockIdx.x * 16;
  {
    int nl = tid >> 4, part = tid & 15;  // 16 threads/row, 4 cols each
    int gn = n0 + nl;
    float inv = 1.0f;
    if (gn < N) inv = 1.0f / fmaxf(deg[gn], 1.0f);
    int o = part * 4;
    float4 av = make_float4(0.f, 0.f, 0.f, 0.f);
    float4 rv = make_float4(0.f, 0.f, 0.f, 0.f);
    if (gn < N) {
      av = *(const float4*)(agg + (size_t)gn * 64 + o);
      rv = *(const float4*)(R + (size_t)gn * 320 + o);
    }
    float4 bv = *(const float4*)(bconv + o);
    float m0 = fmaxf(av.x * inv + rv.x + bv.x, 0.0f);
    float m1 = fmaxf(av.y * inv + rv.y + bv.y, 0.0f);
    float m2 = fmaxf(av.z * inv + rv.z + bv.z, 0.0f);
    float m3 = fmaxf(av.w * inv + rv.w + bv.w, 0.0f);
    int base = nl * 72 + o;
    unsigned short h;
    h = f2bf(m0); Mh[base + 0] = h; Ml[base + 0] = f2bf(m0 - bf2f(h));
    h = f2bf(m1); Mh[base + 1] = h; Ml[base + 1] = f2bf(m1 - bf2f(h));
    h = f2bf(m2); Mh[base + 2] = h; Ml[base + 2] = f2bf(m2 - bf2f(h));
    h = f2bf(m3); Mh[base + 3] = h; Ml[base + 3] = f2bf(m3 - bf2f(h));
    if (gn < N)
      *(float4*)(agg + (size_t)gn * 64 + o) = make_float4(0.f, 0.f, 0.f, 0.f);
  }
  __syncthreads();
  int lane = tid & 63, wave = tid >> 6;
  int quad = lane >> 4, mcol = lane & 15;
  short8 ah[2], al[2];
  #pragma unroll
  for (int kk = 0; kk < 2; ++kk) {
    ah[kk] = *(const short8*)&Mh[mcol * 72 + kk * 32 + quad * 8];
    al[kk] = *(const short8*)&Ml[mcol * 72 + kk * 32 + quad * 8];
  }
  int c = wave * 16 + mcol;
  f32x4 accg[3];
  #pragma unroll 1
  for (int g = 0; g < 3; ++g) {
    const unsigned short* bhp = Wih_fh + (size_t)g * 4096 + wave * 1024 + lane * 8;
    const unsigned short* blp = Wih_fl + (size_t)g * 4096 + wave * 1024 + lane * 8;
    short8 bh0 = *(const short8*)bhp, bh1 = *(const short8*)(bhp + 512);
    short8 bl0 = *(const short8*)blp, bl1 = *(const short8*)(blp + 512);
    f32x4 p = (f32x4){0.f, 0.f, 0.f, 0.f};
    p = MFMA(al[0], bh0, p);
    p = MFMA(ah[0], bl0, p);
    p = MFMA(ah[0], bh0, p);
    p = MFMA(al[1], bh1, p);
    p = MFMA(ah[1], bl1, p);
    p = MFMA(ah[1], bh1, p);
    accg[g] = p;
  }
  float bir = b_ih[c], biz = b_ih[64 + c], bin = b_ih[128 + c];
  float bhr = b_hh[c], bhz = b_hh[64 + c], bhn = b_hh[128 + c];
  float hnew[4];
  #pragma unroll
  for (int r = 0; r < 4; ++r) {
    int node = n0 + quad * 4 + r;
    hnew[r] = 0.0f;
    if (node >= N) continue;
    const float* Rn = R + (size_t)node * 320;
    float gir = accg[0][r] + bir + Rn[64 + c] + bhr;
    float giz = accg[1][r] + biz + Rn[128 + c] + bhz;
    float ghn = Rn[192 + c] + bhn;
    float rg = 1.0f / (1.0f + expf(-gir));
    float zg = 1.0f / (1.0f + expf(-giz));
    float ng = tanhf(accg[2][r] + bin + rg * ghn);
    size_t si = (size_t)node * 64 + c;
    float h = state[si];
    float hv = (1.0f - zg) * ng + zg * h;
    state[si] = hv;
    hnew[r] = hv;
  }
  if (!do_pre) return;
  __syncthreads();  // all Mh/Ml A-frag reads done -> reuse for h_new
  #pragma unroll
  for (int r = 0; r < 4; ++r) {
    int base = (quad * 4 + r) * 72 + c;
    float v = hnew[r];
    unsigned short h = f2bf(v);
    Mh[base] = h; Ml[base] = f2bf(v - bf2f(h));
  }
  __syncthreads();
  // pre phase: R = h_new @ Wc^T ; wave covers cols [80w, 80w+80)
  short8 ph[2], pl[2];
  #pragma unroll
  for (int kk = 0; kk < 2; ++kk) {
    ph[kk] = *(const short8*)&Mh[mcol * 72 + kk * 32 + quad * 8];
    pl[kk] = *(const short8*)&Ml[mcol * 72 + kk * 32 + quad * 8];
  }
  #pragma unroll 1
  for (int cg = 0; cg < 5; ++cg) {
    int cc = wave * 80 + cg * 16 + mcol;
    const unsigned short* bhp = Wc_fh + (size_t)(wave * 5 + cg) * 1024 + lane * 8;
    const unsigned short* blp = Wc_fl + (size_t)(wave * 5 + cg) * 1024 + lane * 8;
    short8 bh0 = *(const short8*)bhp, bh1 = *(const short8*)(bhp + 512);
    short8 bl0 = *(const short8*)blp, bl1 = *(const short8*)(blp + 512);
    f32x4 p = (f32x4){0.f, 0.f, 0.f, 0.f};
    p = MFMA(pl[0], bh0, p);
    p = MFMA(ph[0], bl0, p);
    p = MFMA(ph[0], bh0, p);
    p = MFMA(pl[1], bh1, p);
    p = MFMA(ph[1], bl1, p);
    p = MFMA(ph[1], bh1, p);
    #pragma unroll
    for (int r = 0; r < 4; ++r) {
      int row = n0 + quad * 4 + r;
      if (row < N) R[(size_t)row * 320 + cc] = p[r];
    }
  }
}

// out = relu(cat(h, graph_attr[batch]) @ W1^T + b1) @ W2^T + b2. One wave per node.
__global__ __launch_bounds__(256) void final_kernel(const float* __restrict__ state,
    const int* __restrict__ batch, const float* __restrict__ gattr,
    const float* __restrict__ W1, const float* __restrict__ b1,
    const float* __restrict__ W2, const float* __restrict__ b2,
    float* __restrict__ out, int N) {
  int lane = threadIdx.x & 63;
  int n = blockIdx.x * 4 + (threadIdx.x >> 6);
  if (n >= N) return;
  float s = state[(size_t)n * 64 + lane];
  int b = batch[n];
  float acc = b1[lane];
  const float* w = W1 + (size_t)lane * 72;
  for (int i = 0; i < 64; ++i) acc += __shfl(s, i) * w[i];
  const float* gar = gattr + (size_t)b * GDIM;
  #pragma unroll
  for (int j = 0; j < GDIM; ++j) acc += gar[j] * w[64 + j];
  float hid = fmaxf(acc, 0.0f);
  float v = hid * W2[lane];
  #pragma unroll
  for (int off = 32; off > 0; off >>= 1) v += __shfl_xor(v, off);
  if (lane == 0) out[n] = v + b2[0];
}

extern "C" void kernel_launch(void* const* d_in, const int* in_sizes, int n_in,
                              void* d_out, int out_size, void* d_ws, size_t ws_size,
                              hipStream_t stream) {
  const float* x     = (const float*)d_in[0];
  const int*   ei    = (const int*)d_in[1];
  const float* ea    = (const float*)d_in[2];
  const int*   batch = (const int*)d_in[3];
  const float* ga    = (const float*)d_in[4];
  const float* W0    = (const float*)d_in[5];
  const float* b0    = (const float*)d_in[6];
  const float* We1   = (const float*)d_in[7];
  const float* be1   = (const float*)d_in[8];
  const float* We2   = (const float*)d_in[9];
  const float* be2   = (const float*)d_in[10];
  const float* Wroot = (const float*)d_in[11];
  const float* bconv = (const float*)d_in[12];
  const float* W_ih  = (const float*)d_in[13];
  const float* W_hh  = (const float*)d_in[14];
  const float* b_ih  = (const float*)d_in[15];
  const float* b_hh  = (const float*)d_in[16];
  const float* W1    = (const float*)d_in[17];
  const float* b1    = (const float*)d_in[18];
  const float* W2    = (const float*)d_in[19];
  const float* b2    = (const float*)d_in[20];
  int N = in_sizes[0] / FIN;
  int E = in_sizes[1] / 2;
  float* out = (float*)d_out;

  char* p = (char*)d_ws;
  float* state = (float*)p; p += (size_t)N * 64 * 4;
  float* agg   = (float*)p; p += (size_t)N * 64 * 4;
  float* deg   = (float*)p; p += ((size_t)N * 4 + 15) & ~(size_t)15;
  float* R     = (float*)p; p += (size_t)N * 320 * 4;
  unsigned short* hidden = (unsigned short*)p; p += (size_t)E * 128 * 2;
  unsigned short* We2f   = (unsigned short*)p; p += (size_t)4096 * 128 * 2;
  unsigned short* Wc_fh  = (unsigned short*)p; p += 320 * 64 * 2;
  unsigned short* Wc_fl  = (unsigned short*)p; p += 320 * 64 * 2;
  unsigned short* Wih_fh = (unsigned short*)p; p += 192 * 64 * 2;
  unsigned short* Wih_fl = (unsigned short*)p; p += 192 * 64 * 2;

  int tileBlocks32 = (N + 31) / 32;
  int tileBlocks16 = (N + 15) / 16;
  int edgeBlocks = (E + 63) / 64;

  int eB = (E * 128 + 255) / 256;
  int cB = (4096 * 128 + 255) / 256;
  int pB = (32768 + 255) / 256;
  int lB = (N * 64 + 255) / 256;

  zero_f32<<<(N * 65 + 255) / 256, 256, 0, stream>>>(agg, N * 65);  // agg + deg contiguous
  deg_kernel<<<(E + 255) / 256, 256, 0, stream>>>(ei + E, deg, E);
  setup_fused<<<eB + cB + pB + lB, 256, 0, stream>>>(
      ea, We1, be1, hidden, We2, We2f, Wroot, W_hh, be2, W_ih,
      Wc_fh, Wc_fl, Wih_fh, Wih_fl, x, W0, b0, state, E, N, eB, cB, pB);
  pre_kernel<<<tileBlocks32, 256, 0, stream>>>(state, Wc_fh, Wc_fl, R, N);
  for (int t = 0; t < 3; ++t) {
    dim3 mg(edgeBlocks, ISPLIT);
    msg_fused<<<mg, 256, 0, stream>>>(ei, state, hidden, We2f, R, agg, E);
    gate_pre<<<tileBlocks16, 256, 0, stream>>>(agg, deg, state, R, bconv,
                                               Wih_fh, Wih_fl, b_ih, b_hh,
                                               Wc_fh, Wc_fl, N, (t < 2) ? 1 : 0);
  }
  final_kernel<<<(N + 3) / 4, 256, 0, stream>>>(state, batch, ga, W1, b1, W2, b2, out, N);
}

// Round 16
// 404.992 us; speedup vs baseline: 1.1013x; 1.0193x over previous
//
#include <hip/hip_runtime.h>
#include <hip/hip_bf16.h>
#include <math.h>

#define FIN 32
#define EFD 16
#define GDIM 8
#define ISPLIT 2
// D = 64, DL = 128 hard-coded throughout

typedef __attribute__((ext_vector_type(8))) short short8;   // 8 bf16 = 4 VGPRs (MFMA A/B frag)
typedef __attribute__((ext_vector_type(4))) float f32x4;    // MFMA C/D frag

static __device__ __forceinline__ float bf2f(unsigned short u) {
  return __uint_as_float(((unsigned)u) << 16);
}
static __device__ __forceinline__ unsigned short f2bf(float f) {
  unsigned u = __float_as_uint(f);
  unsigned r = (u + 0x7FFFu + ((u >> 16) & 1u)) >> 16;  // RNE
  return (unsigned short)r;
}

__global__ void zero_f32(float* __restrict__ p, int n) {
  int i = blockIdx.x * blockDim.x + threadIdx.x;
  if (i < n) p[i] = 0.0f;
}

__global__ void deg_kernel(const int* __restrict__ dst, float* __restrict__ deg, int E) {
  int e = blockIdx.x * blockDim.x + threadIdx.x;
  if (e < E) atomicAdd(&deg[dst[e]], 1.0f);
}

// One launch covering 4 independent setup jobs, partitioned by blockIdx range.
__global__ void setup_fused(const float* __restrict__ ea, const float* __restrict__ We1,
                            const float* __restrict__ be1, unsigned short* __restrict__ hidden,
                            const float* __restrict__ We2, unsigned short* __restrict__ We2f,
                            const float* __restrict__ Wroot, const float* __restrict__ W_hh,
                            const float* __restrict__ be2, const float* __restrict__ W_ih,
                            unsigned short* __restrict__ Wc_fh, unsigned short* __restrict__ Wc_fl,
                            unsigned short* __restrict__ Wih_fh, unsigned short* __restrict__ Wih_fl,
                            const float* __restrict__ x, const float* __restrict__ W0,
                            const float* __restrict__ b0, float* __restrict__ state,
                            int E, int N, int eB, int cB, int pB) {
  int b = blockIdx.x;
  if (b < eB) {
    int idx = b * 256 + threadIdx.x;
    int e = idx >> 7, l = idx & 127;
    if (e >= E) return;
    float acc = be1[l];
    const float* er = ea + (size_t)e * EFD;
    const float* wr = We1 + (size_t)l * EFD;
    #pragma unroll
    for (int j = 0; j < EFD; ++j) acc += er[j] * wr[j];
    hidden[idx] = f2bf(fmaxf(acc, 0.0f));
    return;
  }
  b -= eB;
  if (b < cB) {
    int fidx = b * 256 + threadIdx.x;
    if (fidx >= 4096 * 128) return;
    int j    = fidx & 7;
    int lane = (fidx >> 3) & 63;
    int kk   = (fidx >> 9) & 3;
    int wave = (fidx >> 11) & 3;
    int i    = fidx >> 13;
    int quad = lane >> 4, col = lane & 15;
    int row  = i * 64 + wave * 16 + col;    // 0..4095
    int cw   = kk * 32 + quad * 8 + j;      // 0..127
    We2f[fidx] = f2bf(We2[(size_t)row * 128 + cw]);
    return;
  }
  b -= cB;
  if (b < pB) {
    int idx = b * 256 + threadIdx.x;
    if (idx >= 20480 + 12288) return;
    if (idx < 20480) {
      int j = idx & 7, lane = (idx >> 3) & 63, kk = (idx >> 9) & 1, cgk = idx >> 10;  // 0..19
      int quad = lane >> 4, mcol = lane & 15;
      int wave = cgk / 5, cg = cgk % 5;
      int c = wave * 80 + cg * 16 + mcol;   // 0..319
      int cw = kk * 32 + quad * 8 + j;      // 0..63
      float w;
      if (c < 64)       w = Wroot[c * 64 + cw];
      else if (c < 256) w = W_hh[(c - 64) * 64 + cw];
      else              w = be2[cw * 64 + (c - 256)];
      unsigned short h = f2bf(w);
      Wc_fh[idx] = h;
      Wc_fl[idx] = f2bf(w - bf2f(h));
    } else {
      int t = idx - 20480;
      int j = t & 7, lane = (t >> 3) & 63, kk = (t >> 9) & 1, gw = t >> 10;  // 0..11
      int quad = lane >> 4, mcol = lane & 15;
      int g = gw >> 2, wave = gw & 3;
      int row = g * 64 + wave * 16 + mcol;
      int cw = kk * 32 + quad * 8 + j;
      float w = W_ih[row * 64 + cw];
      unsigned short h = f2bf(w);
      Wih_fh[t] = h;
      Wih_fl[t] = f2bf(w - bf2f(h));
    }
    return;
  }
  b -= pB;
  {
    int idx = b * 256 + threadIdx.x;
    int n = idx >> 6, d = idx & 63;
    if (n >= N) return;
    float acc = b0[d];
    const float* xr = x + (size_t)n * FIN;
    const float* wr = W0 + (size_t)d * FIN;
    #pragma unroll
    for (int f = 0; f < FIN; ++f) acc += xr[f] * wr[f];
    state[idx] = fmaxf(acc, 0.0f);
  }
}

#define MFMA(A, B, C) __builtin_amdgcn_mfma_f32_16x16x32_bf16((A), (B), (C), 0, 0, 0)

// R[N,320] = state @ Wc^T (hi/lo split). 32 nodes/block.
__global__ __launch_bounds__(256) void pre_kernel(const float* __restrict__ state,
    const unsigned short* __restrict__ Wc_fh, const unsigned short* __restrict__ Wc_fl,
    float* __restrict__ R, int N) {
  __shared__ __align__(16) unsigned short Sh[32 * 72], Sl[32 * 72];
  int tid = threadIdx.x;
  int n0 = blockIdx.x * 32;
  {
    int nl = tid >> 3, part = tid & 7;  // 8 threads/row, 8 cols each
    int gn = n0 + nl;
    const float* sp = state + (size_t)gn * 64 + part * 8;
    #pragma unroll
    for (int j = 0; j < 2; ++j) {
      float4 v = make_float4(0.f, 0.f, 0.f, 0.f);
      if (gn < N) v = *(const float4*)(sp + j * 4);
      int base = nl * 72 + part * 8 + j * 4;
      unsigned short h;
      h = f2bf(v.x); Sh[base + 0] = h; Sl[base + 0] = f2bf(v.x - bf2f(h));
      h = f2bf(v.y); Sh[base + 1] = h; Sl[base + 1] = f2bf(v.y - bf2f(h));
      h = f2bf(v.z); Sh[base + 2] = h; Sl[base + 2] = f2bf(v.z - bf2f(h));
      h = f2bf(v.w); Sh[base + 3] = h; Sl[base + 3] = f2bf(v.w - bf2f(h));
    }
  }
  __syncthreads();
  int lane = tid & 63, wave = tid >> 6;
  int quad = lane >> 4, mcol = lane & 15;
  short8 ah[2][2], al[2][2];
  #pragma unroll
  for (int mt = 0; mt < 2; ++mt)
    #pragma unroll
    for (int kk = 0; kk < 2; ++kk) {
      ah[mt][kk] = *(const short8*)&Sh[(mt * 16 + mcol) * 72 + kk * 32 + quad * 8];
      al[mt][kk] = *(const short8*)&Sl[(mt * 16 + mcol) * 72 + kk * 32 + quad * 8];
    }
  int c0w = wave * 80;
  #pragma unroll 1
  for (int cg = 0; cg < 5; ++cg) {
    int c = c0w + cg * 16 + mcol;
    const unsigned short* bhp = Wc_fh + (size_t)(wave * 5 + cg) * 1024 + lane * 8;
    const unsigned short* blp = Wc_fl + (size_t)(wave * 5 + cg) * 1024 + lane * 8;
    short8 bh0 = *(const short8*)bhp, bh1 = *(const short8*)(bhp + 512);
    short8 bl0 = *(const short8*)blp, bl1 = *(const short8*)(blp + 512);
    #pragma unroll
    for (int mt = 0; mt < 2; ++mt) {
      f32x4 p = (f32x4){0.f, 0.f, 0.f, 0.f};
      p = MFMA(al[mt][0], bh0, p);
      p = MFMA(ah[mt][0], bl0, p);
      p = MFMA(ah[mt][0], bh0, p);
      p = MFMA(al[mt][1], bh1, p);
      p = MFMA(ah[mt][1], bl1, p);
      p = MFMA(ah[mt][1], bh1, p);
      #pragma unroll
      for (int r = 0; r < 4; ++r) {
        int row = n0 + mt * 16 + quad * 4 + r;
        if (row < N) R[(size_t)row * 320 + c] = p[r];
      }
    }
  }
}

// Fused NNConv message + scatter — R8/R10/R13 configuration, UNTOUCHED (best
// measured: 77 µs, MfmaUtil 27.5%, VGPR 88, 5 waves/SIMD).
// Negative results pinned here: depth-2 prefetch → VGPR 132, regressed (R9);
// separate-St single-barrier prologue → VGPR 108 + LDS 26K, regressed (R11);
// __launch_bounds__(256,6) → allocator collapse to VGPR 40 + full spill (R12);
// u-bias extraction to appended blocks → dilution, regressed (R14);
// full unroll → 256 VGPR spill (R6). This is the structure's floor.
__global__ __launch_bounds__(256) void msg_fused(const int* __restrict__ ei,
    const float* __restrict__ state, const unsigned short* __restrict__ hidden,
    const unsigned short* __restrict__ We2f, const float* __restrict__ R,
    float* __restrict__ agg, int E) {
  __shared__ __align__(16) char smem[64 * 136 * 2];
  __shared__ int srcs[64], dsts[64];
  unsigned short* Hs = (unsigned short*)smem;
  float* St = (float*)smem;  // [i_local][e], 32*64*4 = 8192 <= 17408
  int tid = threadIdx.x;
  int e0 = blockIdx.x * 64;
  int i0 = blockIdx.y * 32;  // this block's fold range [i0, i0+32)
  if (tid < 64) {
    int e = e0 + tid;
    srcs[tid] = (e < E) ? ei[e] : -1;
    dsts[tid] = (e < E) ? ei[E + e] : -1;
  }
  {
    int er = tid >> 2, part = tid & 3;
    int ge = e0 + er;
    const unsigned short* hp = hidden + (size_t)ge * 128 + part * 32;
    #pragma unroll
    for (int j = 0; j < 4; ++j) {
      uint4 v = make_uint4(0u, 0u, 0u, 0u);
      if (ge < E) v = *(const uint4*)(hp + j * 8);
      *(uint4*)&Hs[er * 136 + part * 32 + j * 8] = v;
    }
  }
  __syncthreads();
  int lane = tid & 63, wave = tid >> 6;
  int n0 = wave * 16;
  int quad = lane >> 4, col = lane & 15;
  short8 a[4][4];
  #pragma unroll
  for (int mt = 0; mt < 4; ++mt)
    #pragma unroll
    for (int kk = 0; kk < 4; ++kk)
      a[mt][kk] = *(const short8*)&Hs[(mt * 16 + col) * 136 + kk * 32 + quad * 8];
  // gather s for i_local range [wave*8, wave*8+8), lane = edge
  float4 sreg[2];
  {
    int sn = srcs[lane];
    const float* sp = state + (size_t)(sn < 0 ? 0 : sn) * 64 + i0 + wave * 8;
    #pragma unroll
    for (int j = 0; j < 2; ++j) {
      float4 v = make_float4(0.f, 0.f, 0.f, 0.f);
      if (sn >= 0) v = *(const float4*)(sp + j * 4);
      sreg[j] = v;
    }
  }
  __syncthreads();  // Hs reads retired -> safe to overwrite with St
  #pragma unroll
  for (int j = 0; j < 2; ++j) {
    int i = wave * 8 + j * 4;
    St[(i + 0) * 64 + lane] = sreg[j].x;
    St[(i + 1) * 64 + lane] = sreg[j].y;
    St[(i + 2) * 64 + lane] = sreg[j].z;
    St[(i + 3) * 64 + lane] = sreg[j].w;
  }
  __syncthreads();

  f32x4 macc0 = (f32x4){0.f,0.f,0.f,0.f}, macc1 = (f32x4){0.f,0.f,0.f,0.f};
  f32x4 macc2 = (f32x4){0.f,0.f,0.f,0.f}, macc3 = (f32x4){0.f,0.f,0.f,0.f};
  // fragment-major: addr = (i0+il)*8192 + wave*2048 + kk*512 + lane*8
  const unsigned short* bptr = We2f + (size_t)i0 * 8192 + wave * 2048 + lane * 8;
  short8 Xa = *(const short8*)(bptr + 0);
  short8 Xb = *(const short8*)(bptr + 512);
  short8 Xc = *(const short8*)(bptr + 1024);
  short8 Xd = *(const short8*)(bptr + 1536);
  short8 Ya, Yb, Yc, Yd;
  #pragma unroll 1
  for (int ii = 0; ii < 16; ++ii) {
    int i = ii * 2;
    {
      const unsigned short* bn = bptr + (size_t)(i + 1) * 8192;
      Ya = *(const short8*)(bn + 0);
      Yb = *(const short8*)(bn + 512);
      Yc = *(const short8*)(bn + 1024);
      Yd = *(const short8*)(bn + 1536);
    }
    {
      f32x4 sv0 = *(const f32x4*)&St[i * 64 +  0 + quad * 4];
      f32x4 sv1 = *(const f32x4*)&St[i * 64 + 16 + quad * 4];
      f32x4 sv2 = *(const f32x4*)&St[i * 64 + 32 + quad * 4];
      f32x4 sv3 = *(const f32x4*)&St[i * 64 + 48 + quad * 4];
      f32x4 p0 = (f32x4){0.f,0.f,0.f,0.f}, p1 = (f32x4){0.f,0.f,0.f,0.f};
      f32x4 p2 = (f32x4){0.f,0.f,0.f,0.f}, p3 = (f32x4){0.f,0.f,0.f,0.f};
      p0 = MFMA(a[0][0], Xa, p0); p1 = MFMA(a[1][0], Xa, p1);
      p2 = MFMA(a[2][0], Xa, p2); p3 = MFMA(a[3][0], Xa, p3);
      p0 = MFMA(a[0][1], Xb, p0); p1 = MFMA(a[1][1], Xb, p1);
      p2 = MFMA(a[2][1], Xb, p2); p3 = MFMA(a[3][1], Xb, p3);
      p0 = MFMA(a[0][2], Xc, p0); p1 = MFMA(a[1][2], Xc, p1);
      p2 = MFMA(a[2][2], Xc, p2); p3 = MFMA(a[3][2], Xc, p3);
      p0 = MFMA(a[0][3], Xd, p0); p1 = MFMA(a[1][3], Xd, p1);
      p2 = MFMA(a[2][3], Xd, p2); p3 = MFMA(a[3][3], Xd, p3);
      macc0 += sv0 * p0; macc1 += sv1 * p1; macc2 += sv2 * p2; macc3 += sv3 * p3;
    }
    if (ii < 15) {
      const unsigned short* bn = bptr + (size_t)(i + 2) * 8192;
      Xa = *(const short8*)(bn + 0);
      Xb = *(const short8*)(bn + 512);
      Xc = *(const short8*)(bn + 1024);
      Xd = *(const short8*)(bn + 1536);
    }
    {
      int io = i + 1;
      f32x4 sv0 = *(const f32x4*)&St[io * 64 +  0 + quad * 4];
      f32x4 sv1 = *(const f32x4*)&St[io * 64 + 16 + quad * 4];
      f32x4 sv2 = *(const f32x4*)&St[io * 64 + 32 + quad * 4];
      f32x4 sv3 = *(const f32x4*)&St[io * 64 + 48 + quad * 4];
      f32x4 p0 = (f32x4){0.f,0.f,0.f,0.f}, p1 = (f32x4){0.f,0.f,0.f,0.f};
      f32x4 p2 = (f32x4){0.f,0.f,0.f,0.f}, p3 = (f32x4){0.f,0.f,0.f,0.f};
      p0 = MFMA(a[0][0], Ya, p0); p1 = MFMA(a[1][0], Ya, p1);
      p2 = MFMA(a[2][0], Ya, p2); p3 = MFMA(a[3][0], Ya, p3);
      p0 = MFMA(a[0][1], Yb, p0); p1 = MFMA(a[1][1], Yb, p1);
      p2 = MFMA(a[2][1], Yb, p2); p3 = MFMA(a[3][1], Yb, p3);
      p0 = MFMA(a[0][2], Yc, p0); p1 = MFMA(a[1][2], Yc, p1);
      p2 = MFMA(a[2][2], Yc, p2); p3 = MFMA(a[3][2], Yc, p3);
      p0 = MFMA(a[0][3], Yd, p0); p1 = MFMA(a[1][3], Yd, p1);
      p2 = MFMA(a[2][3], Yd, p2); p3 = MFMA(a[3][3], Yd, p3);
      macc0 += sv0 * p0; macc1 += sv1 * p1; macc2 += sv2 * p2; macc3 += sv3 * p3;
    }
  }
  int addu = (blockIdx.y == 0);
  f32x4 maccA[4] = {macc0, macc1, macc2, macc3};
  #pragma unroll
  for (int mt = 0; mt < 4; ++mt) {
    #pragma unroll
    for (int r = 0; r < 4; ++r) {
      int el = mt * 16 + quad * 4 + r;
      int d = dsts[el];
      if (d >= 0) {
        float val = maccA[mt][r];
        if (addu) val += R[(size_t)srcs[el] * 320 + 256 + n0 + col];
        atomicAdd(&agg[(size_t)d * 64 + n0 + col], val);
      }
    }
  }
}

// Fused: m = relu(agg/deg + R.root + bconv); gi = m@W_ih^T; gates; re-zero agg;
// then either next iteration's R = h_new @ Wc^T (do_pre), or (final iteration)
// the output head: out = relu(cat(h,ga[batch])@W1^T+b1)@W2+b2 via LDS h.
// 16 nodes/block (626 blocks) — latency-bound, more blocks = more waves.
// (Head-fusion validated in R14: absmax identical; the R14 regression was
// fully attributed to the msg u-extraction, not this branch.)
__global__ __launch_bounds__(256) void gate_pre(float* __restrict__ agg,
    const float* __restrict__ deg, float* __restrict__ state,
    float* __restrict__ R, const float* __restrict__ bconv,
    const unsigned short* __restrict__ Wih_fh, const unsigned short* __restrict__ Wih_fl,
    const float* __restrict__ b_ih, const float* __restrict__ b_hh,
    const unsigned short* __restrict__ Wc_fh, const unsigned short* __restrict__ Wc_fl,
    const int* __restrict__ batch, const float* __restrict__ gattr,
    const float* __restrict__ W1, const float* __restrict__ b1,
    const float* __restrict__ W2, const float* __restrict__ b2,
    float* __restrict__ out, int N, int do_pre) {
  __shared__ __align__(16) unsigned short Mh[16 * 72], Ml[16 * 72];
  int tid = threadIdx.x;
  int n0 = blockIdx.x * 16;
  {
    int nl = tid >> 4, part = tid & 15;  // 16 threads/row, 4 cols each
    int gn = n0 + nl;
    float inv = 1.0f;
    if (gn < N) inv = 1.0f / fmaxf(deg[gn], 1.0f);
    int o = part * 4;
    float4 av = make_float4(0.f, 0.f, 0.f, 0.f);
    float4 rv = make_float4(0.f, 0.f, 0.f, 0.f);
    if (gn < N) {
      av = *(const float4*)(agg + (size_t)gn * 64 + o);
      rv = *(const float4*)(R + (size_t)gn * 320 + o);
    }
    float4 bv = *(const float4*)(bconv + o);
    float m0 = fmaxf(av.x * inv + rv.x + bv.x, 0.0f);
    float m1 = fmaxf(av.y * inv + rv.y + bv.y, 0.0f);
    float m2 = fmaxf(av.z * inv + rv.z + bv.z, 0.0f);
    float m3 = fmaxf(av.w * inv + rv.w + bv.w, 0.0f);
    int base = nl * 72 + o;
    unsigned short h;
    h = f2bf(m0); Mh[base + 0] = h; Ml[base + 0] = f2bf(m0 - bf2f(h));
    h = f2bf(m1); Mh[base + 1] = h; Ml[base + 1] = f2bf(m1 - bf2f(h));
    h = f2bf(m2); Mh[base + 2] = h; Ml[base + 2] = f2bf(m2 - bf2f(h));
    h = f2bf(m3); Mh[base + 3] = h; Ml[base + 3] = f2bf(m3 - bf2f(h));
    if (gn < N)
      *(float4*)(agg + (size_t)gn * 64 + o) = make_float4(0.f, 0.f, 0.f, 0.f);
  }
  __syncthreads();
  int lane = tid & 63, wave = tid >> 6;
  int quad = lane >> 4, mcol = lane & 15;
  short8 ah[2], al[2];
  #pragma unroll
  for (int kk = 0; kk < 2; ++kk) {
    ah[kk] = *(const short8*)&Mh[mcol * 72 + kk * 32 + quad * 8];
    al[kk] = *(const short8*)&Ml[mcol * 72 + kk * 32 + quad * 8];
  }
  int c = wave * 16 + mcol;
  f32x4 accg[3];
  #pragma unroll 1
  for (int g = 0; g < 3; ++g) {
    const unsigned short* bhp = Wih_fh + (size_t)g * 4096 + wave * 1024 + lane * 8;
    const unsigned short* blp = Wih_fl + (size_t)g * 4096 + wave * 1024 + lane * 8;
    short8 bh0 = *(const short8*)bhp, bh1 = *(const short8*)(bhp + 512);
    short8 bl0 = *(const short8*)blp, bl1 = *(const short8*)(blp + 512);
    f32x4 p = (f32x4){0.f, 0.f, 0.f, 0.f};
    p = MFMA(al[0], bh0, p);
    p = MFMA(ah[0], bl0, p);
    p = MFMA(ah[0], bh0, p);
    p = MFMA(al[1], bh1, p);
    p = MFMA(ah[1], bl1, p);
    p = MFMA(ah[1], bh1, p);
    accg[g] = p;
  }
  float bir = b_ih[c], biz = b_ih[64 + c], bin = b_ih[128 + c];
  float bhr = b_hh[c], bhz = b_hh[64 + c], bhn = b_hh[128 + c];
  float hnew[4];
  #pragma unroll
  for (int r = 0; r < 4; ++r) {
    int node = n0 + quad * 4 + r;
    hnew[r] = 0.0f;
    if (node >= N) continue;
    const float* Rn = R + (size_t)node * 320;
    float gir = accg[0][r] + bir + Rn[64 + c] + bhr;
    float giz = accg[1][r] + biz + Rn[128 + c] + bhz;
    float ghn = Rn[192 + c] + bhn;
    float rg = 1.0f / (1.0f + expf(-gir));
    float zg = 1.0f / (1.0f + expf(-giz));
    float ng = tanhf(accg[2][r] + bin + rg * ghn);
    size_t si = (size_t)node * 64 + c;
    float h = state[si];
    float hv = (1.0f - zg) * ng + zg * h;
    state[si] = hv;
    hnew[r] = hv;
  }
  if (do_pre) {
    __syncthreads();  // all Mh/Ml A-frag reads done -> reuse for h_new
    #pragma unroll
    for (int r = 0; r < 4; ++r) {
      int base = (quad * 4 + r) * 72 + c;
      float v = hnew[r];
      unsigned short h = f2bf(v);
      Mh[base] = h; Ml[base] = f2bf(v - bf2f(h));
    }
    __syncthreads();
    // pre phase: R = h_new @ Wc^T ; wave covers cols [80w, 80w+80)
    short8 ph[2], pl[2];
    #pragma unroll
    for (int kk = 0; kk < 2; ++kk) {
      ph[kk] = *(const short8*)&Mh[mcol * 72 + kk * 32 + quad * 8];
      pl[kk] = *(const short8*)&Ml[mcol * 72 + kk * 32 + quad * 8];
    }
    #pragma unroll 1
    for (int cg = 0; cg < 5; ++cg) {
      int cc = wave * 80 + cg * 16 + mcol;
      const unsigned short* bhp = Wc_fh + (size_t)(wave * 5 + cg) * 1024 + lane * 8;
      const unsigned short* blp = Wc_fl + (size_t)(wave * 5 + cg) * 1024 + lane * 8;
      short8 bh0 = *(const short8*)bhp, bh1 = *(const short8*)(bhp + 512);
      short8 bl0 = *(const short8*)blp, bl1 = *(const short8*)(blp + 512);
      f32x4 p = (f32x4){0.f, 0.f, 0.f, 0.f};
      p = MFMA(pl[0], bh0, p);
      p = MFMA(ph[0], bl0, p);
      p = MFMA(ph[0], bh0, p);
      p = MFMA(pl[1], bh1, p);
      p = MFMA(ph[1], bl1, p);
      p = MFMA(ph[1], bh1, p);
      #pragma unroll
      for (int r = 0; r < 4; ++r) {
        int row = n0 + quad * 4 + r;
        if (row < N) R[(size_t)row * 320 + cc] = p[r];
      }
    }
  } else {
    // ---- final head fused into the last gate (h_new via LDS as fp32) ----
    __syncthreads();  // Mh/Ml dead -> overlay Hf (Mh+Ml contiguous, 4608 B)
    float* Hf = (float*)Mh;  // 16*64 floats = 4096 B
    #pragma unroll
    for (int r = 0; r < 4; ++r)
      Hf[(quad * 4 + r) * 64 + c] = hnew[r];
    __syncthreads();
    const float* w = W1 + (size_t)lane * 72;
    #pragma unroll 1
    for (int nl = 0; nl < 4; ++nl) {
      int node_local = wave * 4 + nl;
      int node = n0 + node_local;
      if (node >= N) continue;
      float s = Hf[node_local * 64 + lane];
      int b = batch[node];
      float acc = b1[lane];
      for (int i = 0; i < 64; ++i) acc += __shfl(s, i) * w[i];
      const float* gar = gattr + (size_t)b * GDIM;
      #pragma unroll
      for (int j = 0; j < GDIM; ++j) acc += gar[j] * w[64 + j];
      float hid = fmaxf(acc, 0.0f);
      float v = hid * W2[lane];
      #pragma unroll
      for (int off = 32; off > 0; off >>= 1) v += __shfl_xor(v, off);
      if (lane == 0) out[node] = v + b2[0];
    }
  }
}

extern "C" void kernel_launch(void* const* d_in, const int* in_sizes, int n_in,
                              void* d_out, int out_size, void* d_ws, size_t ws_size,
                              hipStream_t stream) {
  const float* x     = (const float*)d_in[0];
  const int*   ei    = (const int*)d_in[1];
  const float* ea    = (const float*)d_in[2];
  const int*   batch = (const int*)d_in[3];
  const float* ga    = (const float*)d_in[4];
  const float* W0    = (const float*)d_in[5];
  const float* b0    = (const float*)d_in[6];
  const float* We1   = (const float*)d_in[7];
  const float* be1   = (const float*)d_in[8];
  const float* We2   = (const float*)d_in[9];
  const float* be2   = (const float*)d_in[10];
  const float* Wroot = (const float*)d_in[11];
  const float* bconv = (const float*)d_in[12];
  const float* W_ih  = (const float*)d_in[13];
  const float* W_hh  = (const float*)d_in[14];
  const float* b_ih  = (const float*)d_in[15];
  const float* b_hh  = (const float*)d_in[16];
  const float* W1    = (const float*)d_in[17];
  const float* b1    = (const float*)d_in[18];
  const float* W2    = (const float*)d_in[19];
  const float* b2    = (const float*)d_in[20];
  int N = in_sizes[0] / FIN;
  int E = in_sizes[1] / 2;
  float* out = (float*)d_out;

  char* p = (char*)d_ws;
  float* state = (float*)p; p += (size_t)N * 64 * 4;
  float* agg   = (float*)p; p += (size_t)N * 64 * 4;
  float* deg   = (float*)p; p += ((size_t)N * 4 + 15) & ~(size_t)15;
  float* R     = (float*)p; p += (size_t)N * 320 * 4;
  unsigned short* hidden = (unsigned short*)p; p += (size_t)E * 128 * 2;
  unsigned short* We2f   = (unsigned short*)p; p += (size_t)4096 * 128 * 2;
  unsigned short* Wc_fh  = (unsigned short*)p; p += 320 * 64 * 2;
  unsigned short* Wc_fl  = (unsigned short*)p; p += 320 * 64 * 2;
  unsigned short* Wih_fh = (unsigned short*)p; p += 192 * 64 * 2;
  unsigned short* Wih_fl = (unsigned short*)p; p += 192 * 64 * 2;

  int tileBlocks32 = (N + 31) / 32;
  int tileBlocks16 = (N + 15) / 16;
  int edgeBlocks = (E + 63) / 64;

  int eB = (E * 128 + 255) / 256;
  int cB = (4096 * 128 + 255) / 256;
  int pB = (32768 + 255) / 256;
  int lB = (N * 64 + 255) / 256;

  zero_f32<<<(N * 65 + 255) / 256, 256, 0, stream>>>(agg, N * 65);  // agg + deg contiguous
  deg_kernel<<<(E + 255) / 256, 256, 0, stream>>>(ei + E, deg, E);
  setup_fused<<<eB + cB + pB + lB, 256, 0, stream>>>(
      ea, We1, be1, hidden, We2, We2f, Wroot, W_hh, be2, W_ih,
      Wc_fh, Wc_fl, Wih_fh, Wih_fl, x, W0, b0, state, E, N, eB, cB, pB);
  pre_kernel<<<tileBlocks32, 256, 0, stream>>>(state, Wc_fh, Wc_fl, R, N);
  for (int t = 0; t < 3; ++t) {
    dim3 mg(edgeBlocks, ISPLIT);
    msg_fused<<<mg, 256, 0, stream>>>(ei, state, hidden, We2f, R, agg, E);
    gate_pre<<<tileBlocks16, 256, 0, stream>>>(agg, deg, state, R, bconv,
                                               Wih_fh, Wih_fl, b_ih, b_hh,
                                               Wc_fh, Wc_fl, batch, ga,
                                               W1, b1, W2, b2, out,
                                               N, (t < 2) ? 1 : 0);
  }
}